// Round 6
// baseline (1255.157 us; speedup 1.0000x reference)
//
#include <hip/hip_runtime.h>
#include <stdint.h>

typedef unsigned short u16;
typedef unsigned int u32;
typedef unsigned long long u64;

#define BB 16
#define CC 32
#define NN 512
#define TT 256
#define NT (NN*TT)            // 131072
#define BCNT (BB*CC*NT)       // 67108864
#define ALPHA 0.05f
#define BETAC 0.95f

typedef __attribute__((ext_vector_type(8))) short short8v;
typedef __attribute__((ext_vector_type(4))) float f32x4;

__device__ __forceinline__ float bf2f(u16 u){ return __uint_as_float(((u32)u) << 16); }
__device__ __forceinline__ u16 f2bf(float f){
    u32 b = __float_as_uint(f);
    u32 r = (b + 0x7FFFu + ((b >> 16) & 1u)) >> 16;
    return (u16)r;
}

// fold (chunk 0..3, col 0..255) onto 16KB LDS: verified round 4 (k4/k6)
__device__ __forceinline__ u32 fold_addr(int chunk, int t){
    int tp = t & 127;
    int cp = chunk + ((t >> 7) << 2);
    int slot = cp ^ (tp & 7) ^ ((tp >> 2) & 7);
    return (u32)((tp * 8 + slot) * 16);
}

// ---------------------------------------------------------------------------
// K0: adj row-normalize -> bf16; bf16 weight prep
__global__ void k0_prep(const float* __restrict__ adj, const float* __restrict__ mlpw,
                        const float* __restrict__ fw, const float* __restrict__ gw,
                        const float* __restrict__ rw,
                        u16* __restrict__ adjb, u16* __restrict__ wcb,
                        u16* __restrict__ fwgb, u16* __restrict__ rwb){
    int i = blockIdx.x;
    int tid = threadIdx.x;
    float a0 = adj[i*NN + tid];
    float a1 = adj[i*NN + tid + 256];
    float s = a0 + a1;
    for (int off = 32; off; off >>= 1) s += __shfl_down(s, off);
    __shared__ float wsum[4];
    if ((tid & 63) == 0) wsum[tid >> 6] = s;
    __syncthreads();
    float inv = 1.0f / (wsum[0] + wsum[1] + wsum[2] + wsum[3] + 1e-8f);
    adjb[i*NN + tid]       = f2bf(a0 * inv);
    adjb[i*NN + tid + 256] = f2bf(a1 * inv);
    if (blockIdx.x == 0){
        for (int idx = tid; idx < 1024; idx += 256){
            int o = idx >> 5, c = idx & 31;
            float m0 = mlpw[o*96 + c];
            float m1 = mlpw[o*96 + 32 + c];
            float m2 = mlpw[o*96 + 64 + c];
            wcb[o*96 + c]      = f2bf(m0 + ALPHA*(m1 + m2));   // Wh
            wcb[o*96 + 32 + c] = f2bf(BETAC*(m1 + ALPHA*m2));  // W1
            wcb[o*96 + 64 + c] = f2bf(BETAC*BETAC*m2);         // W2
        }
        for (int idx = tid; idx < 2048; idx += 256){
            fwgb[idx]        = f2bf(fw[idx]);
            fwgb[2048 + idx] = f2bf(gw[idx]);
        }
        for (int idx = tid; idx < 1024; idx += 256) rwb[idx] = f2bf(rw[idx]);
    }
}

// ---------------------------------------------------------------------------
// K1 (MFMA): [filt;gate][64][t] = W[64x64] · xpair[64][t] per (b,n); h=tanh*sig
// (unchanged, writes h normal layout [c][n][t])
__global__ __launch_bounds__(256) void k1_mfma(
    const float* __restrict__ x, const u16* __restrict__ fwgb,
    const float* __restrict__ fb, const float* __restrict__ gb,
    u16* __restrict__ hOut){
    __shared__ __align__(16) float xs[CC][265];
    __shared__ float fbl[CC], gbl[CC];
    const int tid = threadIdx.x;
    const int lane = tid & 63, w = tid >> 6;
    const int g = lane >> 4, c16 = lane & 15;
    const int n = blockIdx.x, b = blockIdx.y;
    if (tid < CC){ fbl[tid] = fb[tid]; gbl[tid] = gb[tid]; }
    const float* xb = x + (size_t)(b*CC)*NT + (size_t)n*TT;
    {
        int c = tid >> 3, l8 = tid & 7;
        #pragma unroll
        for (int i = 0; i < 8; ++i){
            float4 v = *(const float4*)(xb + (size_t)c*NT + i*32 + l8*4);
            *(float4*)&xs[c][i*32 + l8*4] = v;
        }
        if (tid < CC) xs[tid][256] = 0.0f;   // causal zero-pad
    }
    __syncthreads();
    f32x4 acc[4][4];
    #pragma unroll
    for (int mi = 0; mi < 4; ++mi)
        #pragma unroll
        for (int ni = 0; ni < 4; ++ni) acc[mi][ni] = (f32x4){0.f,0.f,0.f,0.f};
    #pragma unroll
    for (int kc = 0; kc < 2; ++kc){
        short8v bfr[4];
        #pragma unroll
        for (int ni = 0; ni < 4; ++ni){
            int t = w*64 + ni*16 + c16;
            union { u16 e[8]; short8v v; } bu;
            #pragma unroll
            for (int i = 0; i < 4; ++i){
                int c = kc*16 + g*4 + i;
                bu.e[2*i]   = f2bf(xs[c][t]);
                bu.e[2*i+1] = f2bf(xs[c][t+1]);
            }
            bfr[ni] = bu.v;
        }
        short8v a[4];
        #pragma unroll
        for (int mi = 0; mi < 4; ++mi)
            a[mi] = *(const short8v*)(fwgb + (mi*16 + c16)*64 + kc*32 + g*8);
        #pragma unroll
        for (int mi = 0; mi < 4; ++mi)
            #pragma unroll
            for (int ni = 0; ni < 4; ++ni)
                acc[mi][ni] = __builtin_amdgcn_mfma_f32_16x16x32_bf16(
                    a[mi], bfr[ni], acc[mi][ni], 0, 0, 0);
    }
    u16* hb = hOut + (size_t)(b*CC)*NT + (size_t)n*TT;
    #pragma unroll
    for (int mi = 0; mi < 2; ++mi)
        #pragma unroll
        for (int r = 0; r < 4; ++r){
            int o = mi*16 + g*4 + r;
            float fbv = fbl[o], gbv = gbl[o];
            #pragma unroll
            for (int ni = 0; ni < 4; ++ni){
                int t = w*64 + ni*16 + c16;
                float fa = acc[mi][ni][r] + fbv;
                float ga = acc[mi+2][ni][r] + gbv;
                float th = 1.0f - 2.0f / (__expf(2.0f*fa) + 1.0f);
                float sg = 1.0f / (1.0f + __expf(-ga));
                hb[(size_t)o*NT + t] = f2bf(th * sg);
            }
        }
}

// ---------------------------------------------------------------------------
// KT1: transpose h [bc][n][t] -> hT [bc][t][n], 64x64 tiles
__global__ __launch_bounds__(256) void kT1(const u16* __restrict__ hn, u16* __restrict__ ht){
    __shared__ __align__(16) u16 tile[64][72];   // row = 144B, 16B-aligned
    const int bc = blockIdx.z;
    const int n0 = blockIdx.x * 64;
    const int t0 = blockIdx.y * 64;
    const int tid = threadIdx.x;
    const int r = tid >> 2, cq = tid & 3;
    const u16* src = hn + (size_t)bc*NT + (size_t)(n0 + r)*TT + t0 + cq*16;
    uint4 v0 = *(const uint4*)src;
    uint4 v1 = *(const uint4*)(src + 8);
    *(uint4*)&tile[r][cq*16]     = v0;
    *(uint4*)&tile[r][cq*16 + 8] = v1;
    __syncthreads();
    u16* dst = ht + (size_t)bc*NT + (size_t)(t0 + r)*NN + n0 + cq*16;
    union { u16 e[16]; uint4 q[2]; } o;
    #pragma unroll
    for (int i = 0; i < 16; ++i) o.e[i] = tile[cq*16 + i][r];
    *(uint4*)dst       = o.q[0];
    *(uint4*)(dst + 8) = o.q[1];
}

// ---------------------------------------------------------------------------
// K2 (MFMA, t-major, no LDS / no barriers):
//   dstT[bc][t][i] = sum_j adjb[i][j] * srcT[bc][t][j]
// A and B fragments are direct 16B global loads (L2-resident with XCD swizzle).
__global__ __launch_bounds__(256) void k2_mfma(
    const u16* __restrict__ adjb, const u16* __restrict__ srcT, u16* __restrict__ dstT){
    const int tid = threadIdx.x;
    const int lane = tid & 63, w = tid >> 6;
    const int wm = w >> 1, wn = w & 1;
    const int g = lane >> 4, c16 = lane & 15;
    // XCD-contiguous mapping (verified round 5: FETCH 265->76MB)
    const u32 flat = blockIdx.x;                  // 0..4095
    const u32 work = (flat & 7u) * 512u + (flat >> 3);
    const int bc = (int)(work >> 3);
    const int sub = (int)(work & 7u);
    const int i0 = (sub >> 1) * 128;
    const int t0 = (sub & 1) * 128;
    const u16* sb = srcT + (size_t)bc * NT;
    u16* db = dstT + (size_t)bc * NT;

    const u16* ar[4];
    const u16* br[4];
    #pragma unroll
    for (int mi = 0; mi < 4; ++mi)
        ar[mi] = adjb + (size_t)(i0 + wm*64 + mi*16 + c16) * NN;
    #pragma unroll
    for (int ni = 0; ni < 4; ++ni)
        br[ni] = sb + (size_t)(t0 + wn*64 + ni*16 + c16) * NN;

    f32x4 acc[4][4];
    #pragma unroll
    for (int mi = 0; mi < 4; ++mi)
        #pragma unroll
        for (int ni = 0; ni < 4; ++ni) acc[mi][ni] = (f32x4){0.f,0.f,0.f,0.f};

    #pragma unroll 2
    for (int kc = 0; kc < 16; ++kc){
        const int kb = kc*32 + g*8;
        short8v a[4], bfr[4];
        #pragma unroll
        for (int mi = 0; mi < 4; ++mi) a[mi] = *(const short8v*)(ar[mi] + kb);
        #pragma unroll
        for (int ni = 0; ni < 4; ++ni) bfr[ni] = *(const short8v*)(br[ni] + kb);
        #pragma unroll
        for (int mi = 0; mi < 4; ++mi)
            #pragma unroll
            for (int ni = 0; ni < 4; ++ni)
                acc[mi][ni] = __builtin_amdgcn_mfma_f32_16x16x32_bf16(
                    a[mi], bfr[ni], acc[mi][ni], 0, 0, 0);
    }

    // D: col=c16 -> t, row=g*4+r -> i (verified r3); write t-major [t][i], 4 i's = uint2
    #pragma unroll
    for (int mi = 0; mi < 4; ++mi)
        #pragma unroll
        for (int ni = 0; ni < 4; ++ni){
            int tt = t0 + wn*64 + ni*16 + c16;
            int ib = i0 + wm*64 + mi*16 + g*4;
            u32 lo = (u32)f2bf(acc[mi][ni][0]) | ((u32)f2bf(acc[mi][ni][1]) << 16);
            u32 hi = (u32)f2bf(acc[mi][ni][2]) | ((u32)f2bf(acc[mi][ni][3]) << 16);
            uint2 q = {lo, hi};
            *(uint2*)(db + (size_t)tt*NN + ib) = q;
        }
}

// ---------------------------------------------------------------------------
// K4 (MFMA): y[32o][col] = Wc[32x96]·[hT;g1T;g2T][96][col] + mlp_b
// cols = 8n x 32t tile (t-major inputs, NORMAL-layout ypre output) + BN partials
__global__ __launch_bounds__(256) void k4_mfma(
    const u16* __restrict__ hT, const u16* __restrict__ g1T, const u16* __restrict__ g2T,
    const u16* __restrict__ wcb, const float* __restrict__ mlpb,
    u16* __restrict__ ypre, float* __restrict__ psum, float* __restrict__ psq){
    __shared__ __align__(16) u16 Bt[3*8192];       // 48 KB
    __shared__ float mbl[CC];
    __shared__ float part[2][4][CC];
    const int tid = threadIdx.x;
    const int lane = tid & 63, w = tid >> 6;
    const int g = lane >> 4, c16 = lane & 15;
    const int bx = blockIdx.x;                 // 0..511
    const int tt8 = bx >> 6;                   // 8 t-tiles
    const int nn64 = bx & 63;                  // 64 n-tiles
    const int t0 = tt8 * 32, n0 = nn64 * 8;
    const int b = blockIdx.y;
    const int blk = b * 512 + bx;
    if (tid < CC) mbl[tid] = mlpb[tid];
    const size_t boff = (size_t)(b*CC)*NT;
    const u16* srcs[3] = { hT + boff, g1T + boff, g2T + boff };
    // repack: thread = (chunk=w, lt=lane&31, la4=(lane>>5)*4); cols (la4+m)*32+lt
    const int chunk = w, lt = lane & 31, la4 = (lane >> 5) * 4;
    #pragma unroll
    for (int s = 0; s < 3; ++s){
        uint2 v[8];
        #pragma unroll
        for (int r = 0; r < 8; ++r){
            int c = chunk*8 + r;
            v[r] = *(const uint2*)(srcs[s] + (size_t)c*NT + (size_t)(t0 + lt)*NN + n0 + la4);
        }
        #pragma unroll
        for (int m = 0; m < 4; ++m){
            int col = (la4 + m)*32 + lt;
            u32 d[4];
            #pragma unroll
            for (int p = 0; p < 4; ++p){
                u32 lo = (m < 2) ? v[2*p].x   : v[2*p].y;
                u32 hi = (m < 2) ? v[2*p+1].x : v[2*p+1].y;
                u32 sh = (m & 1) * 16;
                d[p] = ((lo >> sh) & 0xFFFFu) | (((hi >> sh) & 0xFFFFu) << 16);
            }
            uint4 q = {d[0], d[1], d[2], d[3]};
            *(uint4*)((char*)Bt + s*16384 + fold_addr(chunk, col)) = q;
        }
    }
    short8v a[3][2];
    #pragma unroll
    for (int s = 0; s < 3; ++s)
        #pragma unroll
        for (int mi = 0; mi < 2; ++mi)
            a[s][mi] = *(const short8v*)(wcb + (mi*16 + c16)*96 + s*32 + g*8);
    f32x4 acc[2][4];
    #pragma unroll
    for (int mi = 0; mi < 2; ++mi)
        #pragma unroll
        for (int ni = 0; ni < 4; ++ni) acc[mi][ni] = (f32x4){0.f,0.f,0.f,0.f};
    __syncthreads();
    #pragma unroll
    for (int s = 0; s < 3; ++s){
        short8v bfr[4];
        #pragma unroll
        for (int ni = 0; ni < 4; ++ni){
            int col = w*64 + ni*16 + c16;
            bfr[ni] = *(const short8v*)((const char*)Bt + s*16384 + fold_addr(g, col));
        }
        #pragma unroll
        for (int mi = 0; mi < 2; ++mi)
            #pragma unroll
            for (int ni = 0; ni < 4; ++ni)
                acc[mi][ni] = __builtin_amdgcn_mfma_f32_16x16x32_bf16(
                    a[s][mi], bfr[ni], acc[mi][ni], 0, 0, 0);
    }
    // epilogue: bias, NORMAL-layout bf16 ypre, BN partials
    u16* yb = ypre + boff;
    #pragma unroll
    for (int mi = 0; mi < 2; ++mi)
        #pragma unroll
        for (int r = 0; r < 4; ++r){
            int o = mi*16 + g*4 + r;
            float bias = mbl[o];
            float sv = 0.f, qv = 0.f;
            #pragma unroll
            for (int ni = 0; ni < 4; ++ni){
                int col = w*64 + ni*16 + c16;
                int ln = col >> 5, clt = col & 31;
                float y = acc[mi][ni][r] + bias;
                yb[(size_t)o*NT + (size_t)(n0 + ln)*TT + t0 + clt] = f2bf(y);
                sv += y; qv += y*y;
            }
            #pragma unroll
            for (int m = 1; m < 16; m <<= 1){
                sv += __shfl_xor(sv, m);
                qv += __shfl_xor(qv, m);
            }
            if (c16 == 0){ part[0][w][o] = sv; part[1][w][o] = qv; }
        }
    __syncthreads();
    if (tid < CC){
        psum[(size_t)tid*8192 + blk] = part[0][0][tid] + part[0][1][tid] + part[0][2][tid] + part[0][3][tid];
    } else if (tid < 2*CC){
        int o = tid - CC;
        psq[(size_t)o*8192 + blk] = part[1][0][o] + part[1][1][o] + part[1][2][o] + part[1][3][o];
    }
}

// ---------------------------------------------------------------------------
// K5: finalize BN stats -> per-channel scale/shift (deterministic tree)
__global__ void k5_stats(const float* __restrict__ psum, const float* __restrict__ psq,
                         const float* __restrict__ gamma, const float* __restrict__ beta,
                         float* __restrict__ ss){
    int o = blockIdx.x, tid = threadIdx.x;
    double s = 0.0, q = 0.0;
    for (int k = 0; k < 32; ++k){
        s += (double)psum[(size_t)o*8192 + tid + k*256];
        q += (double)psq [(size_t)o*8192 + tid + k*256];
    }
    __shared__ double sd[256], qd[256];
    sd[tid] = s; qd[tid] = q;
    __syncthreads();
    for (int off = 128; off; off >>= 1){
        if (tid < off){ sd[tid] += sd[tid + off]; qd[tid] += qd[tid + off]; }
        __syncthreads();
    }
    if (tid == 0){
        double cnt = (double)BB * NN * TT;
        double mean = sd[0] / cnt;
        double var  = qd[0] / cnt - mean*mean;
        float scale = gamma[o] * (float)(1.0 / sqrt(var + 1e-5));
        float shift = beta[o] - (float)mean * scale;
        ss[o]      = scale;
        ss[CC + o] = shift;
    }
}

// ---------------------------------------------------------------------------
// K6 (MFMA): res = rwb·x; out = relu(res + rb + scale*ypre + shift)  (unchanged)
__global__ __launch_bounds__(256) void k6_mfma(
    const float* __restrict__ x, const u16* __restrict__ rwb,
    const float* __restrict__ rb, const float* __restrict__ ss,
    const u16* __restrict__ ypre, float* __restrict__ out){
    __shared__ __align__(16) u16 Bt[8192];   // 16 KB
    __shared__ float rbl[CC], ssl[2*CC];
    const int tid = threadIdx.x;
    const int lane = tid & 63, w = tid >> 6;
    const int g = lane >> 4, c16 = lane & 15;
    const int nt0 = blockIdx.x * 256;
    const int b = blockIdx.y;
    if (tid < CC) rbl[tid] = rb[tid];
    if (tid < 2*CC) ssl[tid] = ss[tid];
    const size_t boff = (size_t)(b*CC)*NT;
    const float* xb = x + boff;
    const int chunk = w, tq = lane;
    {
        float vv[8][4];
        #pragma unroll
        for (int r = 0; r < 8; ++r){
            float4 v = *(const float4*)(xb + (size_t)(chunk*8 + r)*NT + nt0 + tq*4);
            vv[r][0] = v.x; vv[r][1] = v.y; vv[r][2] = v.z; vv[r][3] = v.w;
        }
        #pragma unroll
        for (int j = 0; j < 4; ++j){
            u32 d[4];
            #pragma unroll
            for (int p = 0; p < 4; ++p)
                d[p] = (u32)f2bf(vv[2*p][j]) | ((u32)f2bf(vv[2*p+1][j]) << 16);
            uint4 q = {d[0], d[1], d[2], d[3]};
            *(uint4*)((char*)Bt + fold_addr(chunk, tq*4 + j)) = q;
        }
    }
    short8v a[2];
    #pragma unroll
    for (int mi = 0; mi < 2; ++mi)
        a[mi] = *(const short8v*)(rwb + (mi*16 + c16)*32 + g*8);
    f32x4 acc[2][4];
    #pragma unroll
    for (int mi = 0; mi < 2; ++mi)
        #pragma unroll
        for (int ni = 0; ni < 4; ++ni) acc[mi][ni] = (f32x4){0.f,0.f,0.f,0.f};
    __syncthreads();
    {
        short8v bfr[4];
        #pragma unroll
        for (int ni = 0; ni < 4; ++ni){
            int t = w*64 + ni*16 + c16;
            bfr[ni] = *(const short8v*)((const char*)Bt + fold_addr(g, t));
        }
        #pragma unroll
        for (int mi = 0; mi < 2; ++mi)
            #pragma unroll
            for (int ni = 0; ni < 4; ++ni)
                acc[mi][ni] = __builtin_amdgcn_mfma_f32_16x16x32_bf16(
                    a[mi], bfr[ni], acc[mi][ni], 0, 0, 0);
    }
    const u16* yb = ypre + boff;
    float* ob = out + boff;
    #pragma unroll
    for (int mi = 0; mi < 2; ++mi)
        #pragma unroll
        for (int r = 0; r < 4; ++r){
            int o = mi*16 + g*4 + r;
            float sc = ssl[o], sh = ssl[CC + o], rbv = rbl[o];
            #pragma unroll
            for (int ni = 0; ni < 4; ++ni){
                int t = nt0 + w*64 + ni*16 + c16;
                float v = acc[mi][ni][r] + rbv + sc * bf2f(yb[(size_t)o*NT + t]) + sh;
                ob[(size_t)o*NT + t] = v > 0.0f ? v : 0.0f;
            }
        }
}

// ---------------------------------------------------------------------------
extern "C" void kernel_launch(void* const* d_in, const int* in_sizes, int n_in,
                              void* d_out, int out_size, void* d_ws, size_t ws_size,
                              hipStream_t stream){
    const float* x     = (const float*)d_in[0];
    const float* adj   = (const float*)d_in[1];
    const float* fw    = (const float*)d_in[2];
    const float* fb    = (const float*)d_in[3];
    const float* gw    = (const float*)d_in[4];
    const float* gb    = (const float*)d_in[5];
    const float* mlpw  = (const float*)d_in[6];
    const float* mlpb  = (const float*)d_in[7];
    const float* rw    = (const float*)d_in[8];
    const float* rb    = (const float*)d_in[9];
    const float* gamma = (const float*)d_in[10];
    const float* beta  = (const float*)d_in[11];
    float* out = (float*)d_out;

    char* ws = (char*)d_ws;
    u16*   bufA  = (u16*)(ws);                          // h_norm [k1,kT1) then ypre [k4,k6]
    u16*   bufB  = (u16*)(ws + (size_t)BCNT*2);         // hT [kT1,k4]
    char*  p     = ws + (size_t)BCNT*4;
    u16*   adjb  = (u16*)p;            p += (size_t)NN*NN*2;   // 524,288 B
    u16*   wcb   = (u16*)p;            p += 3072*2;
    u16*   fwgb  = (u16*)p;            p += 4096*2;
    u16*   rwb   = (u16*)p;            p += 1024*2;
    float* ssb   = (float*)p;          p += 64*4;
    float* psum  = (float*)p;          p += (size_t)CC*8192*4; // 1 MB
    float* psq   = (float*)p;                                  // 1 MB
    // g1T / g2T staged in the two halves of d_out (both dead before k6 writes)
    u16*   g1T   = (u16*)d_out;
    u16*   g2T   = (u16*)d_out + (size_t)BCNT;

    k0_prep <<<NN, 256, 0, stream>>>(adj, mlpw, fw, gw, rw, adjb, wcb, fwgb, rwb);
    k1_mfma <<<dim3(NN, BB), 256, 0, stream>>>(x, fwgb, fb, gb, bufA);
    kT1     <<<dim3(8, 4, 512), 256, 0, stream>>>(bufA, bufB);
    k2_mfma <<<dim3(4096), 256, 0, stream>>>(adjb, bufB, g1T);
    k2_mfma <<<dim3(4096), 256, 0, stream>>>(adjb, g1T, g2T);
    k4_mfma <<<dim3(512, BB), 256, 0, stream>>>(bufB, g1T, g2T, wcb, mlpb,
                                                bufA, psum, psq);
    k5_stats<<<CC, 256, 0, stream>>>(psum, psq, gamma, beta, ssb);
    k6_mfma <<<dim3(512, BB), 256, 0, stream>>>(x, rwb, rb, ssb, bufA, out);
}

// Round 7
// 650.571 us; speedup vs baseline: 1.9293x; 1.9293x over previous
//
#include <hip/hip_runtime.h>
#include <stdint.h>

typedef unsigned short u16;
typedef unsigned int u32;
typedef unsigned long long u64;

#define BB 16
#define CC 32
#define NN 512
#define TT 256
#define NT (NN*TT)            // 131072
#define BCNT (BB*CC*NT)       // 67108864
#define ALPHA 0.05f
#define BETAC 0.95f

typedef __attribute__((ext_vector_type(8))) short short8v;
typedef __attribute__((ext_vector_type(4))) float f32x4;

__device__ __forceinline__ float bf2f(u16 u){ return __uint_as_float(((u32)u) << 16); }
__device__ __forceinline__ u16 f2bf(float f){
    u32 b = __float_as_uint(f);
    u32 r = (b + 0x7FFFu + ((b >> 16) & 1u)) >> 16;
    return (u16)r;
}

// k2 B-tile LDS slot fn (verified round 3/5)
__device__ __forceinline__ u32 bslot_addr(int chunk, int t){
    int slot = chunk ^ (t & 7) ^ ((t >> 2) & 7);
    return (u32)((t * 8 + slot) * 16);
}
// fold (chunk 0..3, col 0..255) onto 16KB LDS: verified round 4 (k4/k6)
__device__ __forceinline__ u32 fold_addr(int chunk, int t){
    int tp = t & 127;
    int cp = chunk + ((t >> 7) << 2);
    int slot = cp ^ (tp & 7) ^ ((tp >> 2) & 7);
    return (u32)((tp * 8 + slot) * 16);
}

// ---------------------------------------------------------------------------
// K0: adj row-normalize -> bf16; bf16 weight prep
__global__ void k0_prep(const float* __restrict__ adj, const float* __restrict__ mlpw,
                        const float* __restrict__ fw, const float* __restrict__ gw,
                        const float* __restrict__ rw,
                        u16* __restrict__ adjb, u16* __restrict__ wcb,
                        u16* __restrict__ fwgb, u16* __restrict__ rwb){
    int i = blockIdx.x;
    int tid = threadIdx.x;
    float a0 = adj[i*NN + tid];
    float a1 = adj[i*NN + tid + 256];
    float s = a0 + a1;
    for (int off = 32; off; off >>= 1) s += __shfl_down(s, off);
    __shared__ float wsum[4];
    if ((tid & 63) == 0) wsum[tid >> 6] = s;
    __syncthreads();
    float inv = 1.0f / (wsum[0] + wsum[1] + wsum[2] + wsum[3] + 1e-8f);
    adjb[i*NN + tid]       = f2bf(a0 * inv);
    adjb[i*NN + tid + 256] = f2bf(a1 * inv);
    if (blockIdx.x == 0){
        for (int idx = tid; idx < 1024; idx += 256){
            int o = idx >> 5, c = idx & 31;
            float m0 = mlpw[o*96 + c];
            float m1 = mlpw[o*96 + 32 + c];
            float m2 = mlpw[o*96 + 64 + c];
            wcb[o*96 + c]      = f2bf(m0 + ALPHA*(m1 + m2));   // Wh
            wcb[o*96 + 32 + c] = f2bf(BETAC*(m1 + ALPHA*m2));  // W1
            wcb[o*96 + 64 + c] = f2bf(BETAC*BETAC*m2);         // W2
        }
        for (int idx = tid; idx < 2048; idx += 256){
            fwgb[idx]        = f2bf(fw[idx]);
            fwgb[2048 + idx] = f2bf(gw[idx]);
        }
        for (int idx = tid; idx < 1024; idx += 256) rwb[idx] = f2bf(rw[idx]);
    }
}

// ---------------------------------------------------------------------------
// K0b: pre-permute adjb into MFMA A-fragment order.
// frag f = ((it*2+wm)*4+mi)*16+kc; lane l holds A[row][k..k+7] with
// row = it*128+wm*64+mi*16+(l&15), k = kc*32+(l>>4)*8.  adjF[f*512 + l*8].
__global__ void k0b_afrag(const u16* __restrict__ adjb, u16* __restrict__ adjF){
    int f = blockIdx.x;       // 0..511
    int l = threadIdx.x;      // 0..63
    int it = f >> 7, wm = (f >> 6) & 1, mi = (f >> 4) & 3, kc = f & 15;
    int row = it*128 + wm*64 + mi*16 + (l & 15);
    int k   = kc*32 + (l >> 4)*8;
    uint4 v = *(const uint4*)(adjb + (size_t)row*NN + k);
    *(uint4*)(adjF + (size_t)f*512 + l*8) = v;
}

// ---------------------------------------------------------------------------
// K1 (MFMA): [filt;gate][64][t] = W[64x64] · xpair[64][t] per (b,n); h=tanh*sig
__global__ __launch_bounds__(256) void k1_mfma(
    const float* __restrict__ x, const u16* __restrict__ fwgb,
    const float* __restrict__ fb, const float* __restrict__ gb,
    u16* __restrict__ hOut){
    __shared__ __align__(16) float xs[CC][265];
    __shared__ float fbl[CC], gbl[CC];
    const int tid = threadIdx.x;
    const int lane = tid & 63, w = tid >> 6;
    const int g = lane >> 4, c16 = lane & 15;
    const int n = blockIdx.x, b = blockIdx.y;
    if (tid < CC){ fbl[tid] = fb[tid]; gbl[tid] = gb[tid]; }
    const float* xb = x + (size_t)(b*CC)*NT + (size_t)n*TT;
    {
        int c = tid >> 3, l8 = tid & 7;
        #pragma unroll
        for (int i = 0; i < 8; ++i){
            float4 v = *(const float4*)(xb + (size_t)c*NT + i*32 + l8*4);
            *(float4*)&xs[c][i*32 + l8*4] = v;
        }
        if (tid < CC) xs[tid][256] = 0.0f;   // causal zero-pad
    }
    __syncthreads();
    f32x4 acc[4][4];
    #pragma unroll
    for (int mi = 0; mi < 4; ++mi)
        #pragma unroll
        for (int ni = 0; ni < 4; ++ni) acc[mi][ni] = (f32x4){0.f,0.f,0.f,0.f};
    #pragma unroll
    for (int kc = 0; kc < 2; ++kc){
        short8v bfr[4];
        #pragma unroll
        for (int ni = 0; ni < 4; ++ni){
            int t = w*64 + ni*16 + c16;
            union { u16 e[8]; short8v v; } bu;
            #pragma unroll
            for (int i = 0; i < 4; ++i){
                int c = kc*16 + g*4 + i;
                bu.e[2*i]   = f2bf(xs[c][t]);
                bu.e[2*i+1] = f2bf(xs[c][t+1]);
            }
            bfr[ni] = bu.v;
        }
        short8v a[4];
        #pragma unroll
        for (int mi = 0; mi < 4; ++mi)
            a[mi] = *(const short8v*)(fwgb + (mi*16 + c16)*64 + kc*32 + g*8);
        #pragma unroll
        for (int mi = 0; mi < 4; ++mi)
            #pragma unroll
            for (int ni = 0; ni < 4; ++ni)
                acc[mi][ni] = __builtin_amdgcn_mfma_f32_16x16x32_bf16(
                    a[mi], bfr[ni], acc[mi][ni], 0, 0, 0);
    }
    u16* hb = hOut + (size_t)(b*CC)*NT + (size_t)n*TT;
    #pragma unroll
    for (int mi = 0; mi < 2; ++mi)
        #pragma unroll
        for (int r = 0; r < 4; ++r){
            int o = mi*16 + g*4 + r;
            float fbv = fbl[o], gbv = gbl[o];
            #pragma unroll
            for (int ni = 0; ni < 4; ++ni){
                int t = w*64 + ni*16 + c16;
                float fa = acc[mi][ni][r] + fbv;
                float ga = acc[mi+2][ni][r] + gbv;
                float th = 1.0f - 2.0f / (__expf(2.0f*fa) + 1.0f);
                float sg = 1.0f / (1.0f + __expf(-ga));
                hb[(size_t)o*NT + t] = f2bf(th * sg);
            }
        }
}

// ---------------------------------------------------------------------------
// K2 (MFMA): dst[bc][i][t] = sum_j adj[i][j]*src[bc][j][t]
// Round-7: A-fragments from adjF (fragment-order, lane-contiguous 16B loads,
// L2-resident). B reg-staged repack + LDS dbuf (round-5 proven). XCD swizzle.
template<int DSTF32>
__global__ __launch_bounds__(256) void k2_mfma(
    const u16* __restrict__ adjF, const u16* __restrict__ src, void* __restrict__ dst){
    __shared__ __align__(16) u16 Bl[2][128*64];   // 2 x 16 KB
    const int tid = threadIdx.x;
    const int lane = tid & 63, w = tid >> 6;
    const int wm = w >> 1, wn = w & 1;
    const int g = lane >> 4, c16 = lane & 15;
    // XCD-contiguous mapping (verified round 5: FETCH 265->76MB)
    const u32 flat = blockIdx.x;                  // 0..4095
    const u32 work = (flat & 7u) * 512u + (flat >> 3);
    const int bc = (int)(work >> 3);
    const int sub = (int)(work & 7u);
    const int it = sub >> 1;
    const int i0 = it * 128;
    const int t0 = (sub & 1) * 128;
    const u16* srcb = src + (size_t)bc * NT;
    const int s_chunk = tid >> 5;
    const int s_tb    = (tid & 31) * 4;
    f32x4 acc[4][4];
    #pragma unroll
    for (int mi = 0; mi < 4; ++mi)
        #pragma unroll
        for (int ni = 0; ni < 4; ++ni) acc[mi][ni] = (f32x4){0.f,0.f,0.f,0.f};
    // A-fragment pointers: frag f = ((it*2+wm)*4+mi)*16 + kc16, lane-contig 16B
    const u16* afr[4];
    #pragma unroll
    for (int mi = 0; mi < 4; ++mi)
        afr[mi] = adjF + (size_t)(((it*2 + wm)*4 + mi)*16)*512 + lane*8;

    // prologue: load step 0
    uint2 v[8];
    #pragma unroll
    for (int r = 0; r < 8; ++r)
        v[r] = *(const uint2*)(srcb + (size_t)(s_chunk*8 + r)*TT + t0 + s_tb);

    for (int step = 0; step < 8; ++step){
        const int k0 = step * 64;
        char* bbase = (char*)Bl + (size_t)(step & 1) * 16384;
        // ---- repack current step's registers into LDS buf[cur] ----
        #pragma unroll
        for (int j = 0; j < 4; ++j){
            u32 d[4];
            #pragma unroll
            for (int p = 0; p < 4; ++p){
                u32 lo = (j < 2) ? v[2*p].x   : v[2*p].y;
                u32 hi = (j < 2) ? v[2*p+1].x : v[2*p+1].y;
                u32 sh = (j & 1) * 16;
                d[p] = ((lo >> sh) & 0xFFFFu) | (((hi >> sh) & 0xFFFFu) << 16);
            }
            uint4 q = {d[0], d[1], d[2], d[3]};
            *(uint4*)(bbase + bslot_addr(s_chunk, s_tb + j)) = q;
        }
        // ---- issue next step's global loads (latency hides under compute) ----
        if (step < 7){
            const int k0n = k0 + 64;
            #pragma unroll
            for (int r = 0; r < 8; ++r)
                v[r] = *(const uint2*)(srcb + (size_t)(k0n + s_chunk*8 + r)*TT + t0 + s_tb);
        }
        __syncthreads();
        // ---- compute from buf[cur] ----
        #pragma unroll
        for (int kc = 0; kc < 2; ++kc){
            const int kc16 = step*2 + kc;
            short8v a[4];
            #pragma unroll
            for (int mi = 0; mi < 4; ++mi)
                a[mi] = *(const short8v*)(afr[mi] + kc16*512);
            short8v bfr[4];
            #pragma unroll
            for (int ni = 0; ni < 4; ++ni){
                int t_loc = wn*64 + ni*16 + c16;
                bfr[ni] = *(const short8v*)(bbase + bslot_addr(kc*4 + g, t_loc));
            }
            #pragma unroll
            for (int mi = 0; mi < 4; ++mi)
                #pragma unroll
                for (int ni = 0; ni < 4; ++ni)
                    acc[mi][ni] = __builtin_amdgcn_mfma_f32_16x16x32_bf16(
                        a[mi], bfr[ni], acc[mi][ni], 0, 0, 0);
        }
    }
    if (DSTF32){
        float* d = (float*)dst + (size_t)bc * NT;
        #pragma unroll
        for (int mi = 0; mi < 4; ++mi)
            #pragma unroll
            for (int ni = 0; ni < 4; ++ni){
                int tt = t0 + wn*64 + ni*16 + c16;
                int ib = i0 + wm*64 + mi*16 + g*4;
                #pragma unroll
                for (int r = 0; r < 4; ++r)
                    d[(size_t)(ib + r)*TT + tt] = acc[mi][ni][r];
            }
    } else {
        u16* d = (u16*)dst + (size_t)bc * NT;
        #pragma unroll
        for (int mi = 0; mi < 4; ++mi)
            #pragma unroll
            for (int ni = 0; ni < 4; ++ni){
                int tt = t0 + wn*64 + ni*16 + c16;
                int ib = i0 + wm*64 + mi*16 + g*4;
                #pragma unroll
                for (int r = 0; r < 4; ++r)
                    d[(size_t)(ib + r)*TT + tt] = f2bf(acc[mi][ni][r]);
            }
    }
}

// ---------------------------------------------------------------------------
// K4 (MFMA): y_pre[32][t] = Wc[32x96]·[h;g1;g2][96][t] + mlp_b per (b, 256-nt tile)
// (round-4/5 proven; normal layout; ypre bf16 in place into h_ws)
__global__ __launch_bounds__(256) void k4_mfma(
    const u16* __restrict__ h, const u16* __restrict__ g1, const u16* __restrict__ g2,
    const u16* __restrict__ wcb, const float* __restrict__ mlpb,
    u16* __restrict__ ypre, float* __restrict__ psum, float* __restrict__ psq){
    __shared__ __align__(16) u16 Bt[3*8192];       // 48 KB
    __shared__ float mbl[CC];
    __shared__ float part[2][4][CC];
    const int tid = threadIdx.x;
    const int lane = tid & 63, w = tid >> 6;
    const int g = lane >> 4, c16 = lane & 15;
    const int nt0 = blockIdx.x * 256;
    const int b = blockIdx.y;
    const int blk = b * 512 + blockIdx.x;
    if (tid < CC) mbl[tid] = mlpb[tid];
    const size_t boff = (size_t)(b*CC)*NT;
    const u16* srcs[3] = { h + boff, g1 + boff, g2 + boff };
    const int chunk = w, tq = lane;
    #pragma unroll
    for (int s = 0; s < 3; ++s){
        uint2 v[8];
        #pragma unroll
        for (int r = 0; r < 8; ++r)
            v[r] = *(const uint2*)(srcs[s] + (size_t)(chunk*8 + r)*NT + nt0 + tq*4);
        #pragma unroll
        for (int j = 0; j < 4; ++j){
            u32 d[4];
            #pragma unroll
            for (int p = 0; p < 4; ++p){
                u32 lo = (j < 2) ? v[2*p].x   : v[2*p].y;
                u32 hi = (j < 2) ? v[2*p+1].x : v[2*p+1].y;
                u32 sh = (j & 1) * 16;
                d[p] = ((lo >> sh) & 0xFFFFu) | (((hi >> sh) & 0xFFFFu) << 16);
            }
            uint4 q = {d[0], d[1], d[2], d[3]};
            *(uint4*)((char*)Bt + s*16384 + fold_addr(chunk, tq*4 + j)) = q;
        }
    }
    short8v a[3][2];
    #pragma unroll
    for (int s = 0; s < 3; ++s)
        #pragma unroll
        for (int mi = 0; mi < 2; ++mi)
            a[s][mi] = *(const short8v*)(wcb + (mi*16 + c16)*96 + s*32 + g*8);
    f32x4 acc[2][4];
    #pragma unroll
    for (int mi = 0; mi < 2; ++mi)
        #pragma unroll
        for (int ni = 0; ni < 4; ++ni) acc[mi][ni] = (f32x4){0.f,0.f,0.f,0.f};
    __syncthreads();
    #pragma unroll
    for (int s = 0; s < 3; ++s){
        short8v bfr[4];
        #pragma unroll
        for (int ni = 0; ni < 4; ++ni){
            int t = w*64 + ni*16 + c16;
            bfr[ni] = *(const short8v*)((const char*)Bt + s*16384 + fold_addr(g, t));
        }
        #pragma unroll
        for (int mi = 0; mi < 2; ++mi)
            #pragma unroll
            for (int ni = 0; ni < 4; ++ni)
                acc[mi][ni] = __builtin_amdgcn_mfma_f32_16x16x32_bf16(
                    a[s][mi], bfr[ni], acc[mi][ni], 0, 0, 0);
    }
    u16* yb = ypre + boff;
    #pragma unroll
    for (int mi = 0; mi < 2; ++mi)
        #pragma unroll
        for (int r = 0; r < 4; ++r){
            int o = mi*16 + g*4 + r;
            float bias = mbl[o];
            float sv = 0.f, qv = 0.f;
            #pragma unroll
            for (int ni = 0; ni < 4; ++ni){
                int t = nt0 + w*64 + ni*16 + c16;
                float y = acc[mi][ni][r] + bias;
                yb[(size_t)o*NT + t] = f2bf(y);
                sv += y; qv += y*y;
            }
            #pragma unroll
            for (int m = 1; m < 16; m <<= 1){
                sv += __shfl_xor(sv, m);
                qv += __shfl_xor(qv, m);
            }
            if (c16 == 0){ part[0][w][o] = sv; part[1][w][o] = qv; }
        }
    __syncthreads();
    if (tid < CC){
        psum[(size_t)tid*8192 + blk] = part[0][0][tid] + part[0][1][tid] + part[0][2][tid] + part[0][3][tid];
    } else if (tid < 2*CC){
        int o = tid - CC;
        psq[(size_t)o*8192 + blk] = part[1][0][o] + part[1][1][o] + part[1][2][o] + part[1][3][o];
    }
}

// ---------------------------------------------------------------------------
// K5: finalize BN stats -> per-channel scale/shift (deterministic tree)
__global__ void k5_stats(const float* __restrict__ psum, const float* __restrict__ psq,
                         const float* __restrict__ gamma, const float* __restrict__ beta,
                         float* __restrict__ ss){
    int o = blockIdx.x, tid = threadIdx.x;
    double s = 0.0, q = 0.0;
    for (int k = 0; k < 32; ++k){
        s += (double)psum[(size_t)o*8192 + tid + k*256];
        q += (double)psq [(size_t)o*8192 + tid + k*256];
    }
    __shared__ double sd[256], qd[256];
    sd[tid] = s; qd[tid] = q;
    __syncthreads();
    for (int off = 128; off; off >>= 1){
        if (tid < off){ sd[tid] += sd[tid + off]; qd[tid] += qd[tid + off]; }
        __syncthreads();
    }
    if (tid == 0){
        double cnt = (double)BB * NN * TT;
        double mean = sd[0] / cnt;
        double var  = qd[0] / cnt - mean*mean;
        float scale = gamma[o] * (float)(1.0 / sqrt(var + 1e-5));
        float shift = beta[o] - (float)mean * scale;
        ss[o]      = scale;
        ss[CC + o] = shift;
    }
}

// ---------------------------------------------------------------------------
// K6 (MFMA): res = rwb·x; out = relu(res + rb + scale*ypre + shift)
__global__ __launch_bounds__(256) void k6_mfma(
    const float* __restrict__ x, const u16* __restrict__ rwb,
    const float* __restrict__ rb, const float* __restrict__ ss,
    const u16* __restrict__ ypre, float* __restrict__ out){
    __shared__ __align__(16) u16 Bt[8192];   // 16 KB
    __shared__ float rbl[CC], ssl[2*CC];
    const int tid = threadIdx.x;
    const int lane = tid & 63, w = tid >> 6;
    const int g = lane >> 4, c16 = lane & 15;
    const int nt0 = blockIdx.x * 256;
    const int b = blockIdx.y;
    if (tid < CC) rbl[tid] = rb[tid];
    if (tid < 2*CC) ssl[tid] = ss[tid];
    const size_t boff = (size_t)(b*CC)*NT;
    const float* xb = x + boff;
    const int chunk = w, tq = lane;
    {
        float vv[8][4];
        #pragma unroll
        for (int r = 0; r < 8; ++r){
            float4 v = *(const float4*)(xb + (size_t)(chunk*8 + r)*NT + nt0 + tq*4);
            vv[r][0] = v.x; vv[r][1] = v.y; vv[r][2] = v.z; vv[r][3] = v.w;
        }
        #pragma unroll
        for (int j = 0; j < 4; ++j){
            u32 d[4];
            #pragma unroll
            for (int p = 0; p < 4; ++p)
                d[p] = (u32)f2bf(vv[2*p][j]) | ((u32)f2bf(vv[2*p+1][j]) << 16);
            uint4 q = {d[0], d[1], d[2], d[3]};
            *(uint4*)((char*)Bt + fold_addr(chunk, tq*4 + j)) = q;
        }
    }
    short8v a[2];
    #pragma unroll
    for (int mi = 0; mi < 2; ++mi)
        a[mi] = *(const short8v*)(rwb + (mi*16 + c16)*32 + g*8);
    f32x4 acc[2][4];
    #pragma unroll
    for (int mi = 0; mi < 2; ++mi)
        #pragma unroll
        for (int ni = 0; ni < 4; ++ni) acc[mi][ni] = (f32x4){0.f,0.f,0.f,0.f};
    __syncthreads();
    {
        short8v bfr[4];
        #pragma unroll
        for (int ni = 0; ni < 4; ++ni){
            int t = w*64 + ni*16 + c16;
            bfr[ni] = *(const short8v*)((const char*)Bt + fold_addr(g, t));
        }
        #pragma unroll
        for (int mi = 0; mi < 2; ++mi)
            #pragma unroll
            for (int ni = 0; ni < 4; ++ni)
                acc[mi][ni] = __builtin_amdgcn_mfma_f32_16x16x32_bf16(
                    a[mi], bfr[ni], acc[mi][ni], 0, 0, 0);
    }
    const u16* yb = ypre + boff;
    float* ob = out + boff;
    #pragma unroll
    for (int mi = 0; mi < 2; ++mi)
        #pragma unroll
        for (int r = 0; r < 4; ++r){
            int o = mi*16 + g*4 + r;
            float sc = ssl[o], sh = ssl[CC + o], rbv = rbl[o];
            #pragma unroll
            for (int ni = 0; ni < 4; ++ni){
                int t = nt0 + w*64 + ni*16 + c16;
                float v = acc[mi][ni][r] + rbv + sc * bf2f(yb[(size_t)o*NT + t]) + sh;
                ob[(size_t)o*NT + t] = v > 0.0f ? v : 0.0f;
            }
        }
}

// ---------------------------------------------------------------------------
extern "C" void kernel_launch(void* const* d_in, const int* in_sizes, int n_in,
                              void* d_out, int out_size, void* d_ws, size_t ws_size,
                              hipStream_t stream){
    const float* x     = (const float*)d_in[0];
    const float* adj   = (const float*)d_in[1];
    const float* fw    = (const float*)d_in[2];
    const float* fb    = (const float*)d_in[3];
    const float* gw    = (const float*)d_in[4];
    const float* gb    = (const float*)d_in[5];
    const float* mlpw  = (const float*)d_in[6];
    const float* mlpb  = (const float*)d_in[7];
    const float* rw    = (const float*)d_in[8];
    const float* rb    = (const float*)d_in[9];
    const float* gamma = (const float*)d_in[10];
    const float* beta  = (const float*)d_in[11];
    float* out = (float*)d_out;

    char* ws = (char*)d_ws;
    u16*   h_ws  = (u16*)(ws);                          // h, then ypre in place
    u16*   g1_ws = (u16*)(ws + (size_t)BCNT*2);
    char*  p     = ws + (size_t)BCNT*4;
    u16*   adjb  = (u16*)p;            p += (size_t)NN*NN*2;   // 512 KB
    u16*   adjF  = (u16*)p;            p += (size_t)NN*NN*2;   // 512 KB fragment-order
    u16*   wcb   = (u16*)p;            p += 3072*2;
    u16*   fwgb  = (u16*)p;            p += 4096*2;
    u16*   rwb   = (u16*)p;            p += 1024*2;
    float* ssb   = (float*)p;          p += 64*4;
    float* psum  = (float*)p;          p += (size_t)CC*8192*4; // 1 MB
    float* psq   = (float*)p;                                  // 1 MB
    u16*   g2b   = (u16*)d_out;        // g2 bf16 staged in d_out, consumed by k4

    k0_prep <<<NN, 256, 0, stream>>>(adj, mlpw, fw, gw, rw, adjb, wcb, fwgb, rwb);
    k0b_afrag<<<512, 64, 0, stream>>>(adjb, adjF);
    k1_mfma <<<dim3(NN, BB), 256, 0, stream>>>(x, fwgb, fb, gb, h_ws);
    k2_mfma<0><<<dim3(4096), 256, 0, stream>>>(adjF, h_ws, (void*)g1_ws);
    k2_mfma<0><<<dim3(4096), 256, 0, stream>>>(adjF, g1_ws, (void*)g2b);
    k4_mfma <<<dim3(512, BB), 256, 0, stream>>>(h_ws, g1_ws, g2b, wcb, mlpb,
                                                h_ws, psum, psq);
    k5_stats<<<CC, 256, 0, stream>>>(psum, psq, gamma, beta, ssb);
    k6_mfma <<<dim3(512, BB), 256, 0, stream>>>(x, rwb, rb, ssb, h_ws, out);
}